// Round 12
// baseline (767.792 us; speedup 1.0000x reference)
//
#include <hip/hip_runtime.h>
#include <hip/hip_bf16.h>
#include <stdint.h>

typedef short bf16x8 __attribute__((ext_vector_type(8)));
typedef float f32x4 __attribute__((ext_vector_type(4)));

__device__ __forceinline__ unsigned short f2bf(float x) {
  uint32_t u = __builtin_bit_cast(uint32_t, x);
  u += 0x7FFFu + ((u >> 16) & 1u);
  return (unsigned short)(u >> 16);
}
__device__ __forceinline__ float bf2f(unsigned short u) {
  uint32_t v = ((uint32_t)u) << 16;
  return __builtin_bit_cast(float, v);
}

__device__ __forceinline__ void gl2lds16(const void* g, void* l) {
  __builtin_amdgcn_global_load_lds(
      (const __attribute__((address_space(1))) unsigned int*)g,
      (__attribute__((address_space(3))) unsigned int*)l, 16, 0, 0);
}

__global__ __launch_bounds__(256) void cast_f32_bf16_k(
    const float* __restrict__ s, unsigned short* __restrict__ d, long n) {
  long i = ((long)blockIdx.x * 256 + threadIdx.x) * 8;
  if (i >= n) return;
  float4 a = *(const float4*)(s + i);
  float4 b = *(const float4*)(s + i + 4);
  bf16x8 o;
  o[0] = (short)f2bf(a.x); o[1] = (short)f2bf(a.y);
  o[2] = (short)f2bf(a.z); o[3] = (short)f2bf(a.w);
  o[4] = (short)f2bf(b.x); o[5] = (short)f2bf(b.y);
  o[6] = (short)f2bf(b.z); o[7] = (short)f2bf(b.w);
  *(bf16x8*)(d + i) = o;
}

__global__ __launch_bounds__(256) void cast4_f32_bf16_k(
    const float* __restrict__ s0, const float* __restrict__ s1,
    const float* __restrict__ s2, const float* __restrict__ s3,
    unsigned short* __restrict__ d, long n) {
  const float* s = blockIdx.z == 0 ? s0 : blockIdx.z == 1 ? s1 : blockIdx.z == 2 ? s2 : s3;
  long i = ((long)blockIdx.x * 256 + threadIdx.x) * 8;
  if (i >= n) return;
  float4 a = *(const float4*)(s + i);
  float4 b = *(const float4*)(s + i + 4);
  bf16x8 o;
  o[0] = (short)f2bf(a.x); o[1] = (short)f2bf(a.y);
  o[2] = (short)f2bf(a.z); o[3] = (short)f2bf(a.w);
  o[4] = (short)f2bf(b.x); o[5] = (short)f2bf(b.y);
  o[6] = (short)f2bf(b.z); o[7] = (short)f2bf(b.w);
  *(bf16x8*)(d + blockIdx.z * n + i) = o;
}

// ============================================================================
// 256x256 pipelined GEMM, TRANSPOSED OUTPUT:
//   Cfrag[m][n] = sum_k A[m][k]*B[n][k]; dst[col*ldT + row] (coalesced vec4).
// R12 vs R11: 16 MFMA/phase WITHOUT the b2[2] tile-parity double-buffer that
// spilled (R11: ~280 regs > 256 -> scratch, MfmaUtil 0.6%). Phases = (M-half
// x kh): ph0 P0xbA(kh0), ph1 P1xbA, ph2 P0xbB(kh1), ph3 P1xbB. Live frags
// a0,a1,bA,bB = 16 (64 VGPR) + acc 128 -> ~222 total, fits 2 waves/SIMD.
// LGKM ledger (hand-verified): ph0 enter 8 (+4) wait(4); ph1 4 (+4) wait(4),
// post-MFMA +bB[4]; ph2 8 (+4) wait(4); ph3 gate+barrier, +bA/a0-next[8],
// wait(8) drains a1. Staging WAR audit: A(T+1) at ph0 (prior tile's region
// readers drained by its ph3 wait + final barrier); B(T+2) at ph3-START
// (bB readers drained at ph2 wait(4) + ph2-end barrier -- NOT ph1/ph2,
// which would race bB like R9). vm FIFO/tile: A(T+1)x4 @ph0, B(T+2)x4 @ph3;
// gates: steady vmcnt(4) (12->4); tile nt-2: vmcnt(0); tile nt-1: none.
// ============================================================================
template <typename OutT>
__global__ __launch_bounds__(512, 2) void gemm_tt(
    const unsigned short* __restrict__ A, const unsigned short* __restrict__ B,
    OutT* __restrict__ C, int K,
    long sA, long sB, long sC, int ldA, int ldB, int ldT, float alpha) {
  extern __shared__ __align__(16) char smem[];
  const int bz = blockIdx.z;
  const int gx = gridDim.x;
  const int nwg = gx * gridDim.y;  // must be %8==0
  const int idx = blockIdx.y * gx + blockIdx.x;
  const int wg = (idx & 7) * (nwg >> 3) + (idx >> 3);
  const int bm = wg / gx, bn = wg % gx;

  const int tid = threadIdx.x, lane = tid & 63, wave = tid >> 6;
  const int wm = wave >> 2, wn = wave & 3;

  const long ldAb = (long)ldA * 2, ldBb = (long)ldB * 2;
  const char* Ac = (const char*)(A + (long)bz * sA) + (long)bm * 256 * ldAb;
  const char* Bc = (const char*)(B + (long)bz * sB) + (long)bn * 256 * ldBb;
  C += (long)bz * sC;

  const int sr8 = tid >> 3;
  const int scolx = (((tid & 7) ^ ((tid >> 3) & 7)) << 4);  // pre-swizzled col

  auto stageHalf = [&](int t, int op, int h, const char* gbase, long ldb_) {
    char* reg = smem + (((((t & 1) << 1) | op) << 1 | h) << 14);
    const long ktb = (long)t << 7;
#pragma unroll
    for (int c = 0; c < 2; ++c)
      gl2lds16(gbase + (long)(h * 128 + c * 64 + sr8) * ldb_ + ktb + scolx,
               reg + c * 8192 + tid * 16);
  };

  const char* Areg[2] = { smem + ((0 << 2 | wm) << 14),
                          smem + ((1 << 2 | wm) << 14) };
  const char* Breg[2] = { smem + (((0 << 2) | 2 | (wn >> 1)) << 14),
                          smem + (((1 << 2) | 2 | (wn >> 1)) << 14) };
  const int cko[2] = { (((lane >> 4) << 4) ^ ((lane & 7) << 4)),
                       ((64 | ((lane >> 4) << 4)) ^ ((lane & 7) << 4)) };
  const int rowA0 = (lane & 15) * 128;
  const int rowB0 = ((wn & 1) * 64 + (lane & 15)) * 128;

  f32x4 acc[8][4] = {};
  bf16x8 a0[4], a1[4], bA[4], bB[4];

  // prologue: B(0), A(0), B(1) = 12 loads; vmcnt(4) leaves B(1) in flight
  stageHalf(0, 1, 0, Bc, ldBb); stageHalf(0, 1, 1, Bc, ldBb);
  stageHalf(0, 0, 0, Ac, ldAb); stageHalf(0, 0, 1, Ac, ldAb);
  stageHalf(1, 1, 0, Bc, ldBb); stageHalf(1, 1, 1, Bc, ldBb);
  asm volatile("s_waitcnt vmcnt(4)" ::: "memory");
  __builtin_amdgcn_s_barrier();
  // pre-reads for tile 0: bA(kh0)[4] + a0(P0,kh0)[4]  -> 8 outstanding
#pragma unroll
  for (int n = 0; n < 4; ++n)
    bA[n] = *(const bf16x8*)(Breg[0] + rowB0 + n * 2048 + cko[0]);
#pragma unroll
  for (int j = 0; j < 2; ++j)
#pragma unroll
    for (int k2 = 0; k2 < 2; ++k2)
      a0[j * 2 + k2] = *(const bf16x8*)(Areg[0] + rowA0 + (j * 2 + k2) * 2048 + cko[0]);

  const int nt = K >> 6;         // even, >= 4
  const int niter = nt >> 1;
  for (int i = 0; i < niter; ++i) {
    const int u = 2 * i;
    const bool pf = (i + 1 < niter);
#pragma unroll
    for (int d = 0; d < 2; ++d) {
      // ---- ph0: MFMA P0 x bA(kh0); stage A(T+1); issue a1 <- P1,kh0
      if (d == 0 || pf) { stageHalf(u+1+d,0,0,Ac,ldAb); stageHalf(u+1+d,0,1,Ac,ldAb); }
#pragma unroll
      for (int j = 0; j < 4; ++j)
        a1[j] = *(const bf16x8*)(Areg[d] + rowA0 + (4 + j) * 2048 + cko[0]);
      asm volatile("s_waitcnt lgkmcnt(4)" ::: "memory");
      __builtin_amdgcn_sched_barrier(0);
      __builtin_amdgcn_s_setprio(1);
#pragma unroll
      for (int j = 0; j < 4; ++j)
#pragma unroll
        for (int n = 0; n < 4; ++n)
          acc[j][n] = __builtin_amdgcn_mfma_f32_16x16x32_bf16(a0[j], bA[n], acc[j][n], 0, 0, 0);
      __builtin_amdgcn_s_setprio(0);
      __builtin_amdgcn_s_barrier();

      // ---- ph1: MFMA P1 x bA; issue a0 <- P0,kh1; post-MFMA issue bB(kh1)
#pragma unroll
      for (int j = 0; j < 4; ++j)
        a0[j] = *(const bf16x8*)(Areg[d] + rowA0 + j * 2048 + cko[1]);
      asm volatile("s_waitcnt lgkmcnt(4)" ::: "memory");
      __builtin_amdgcn_sched_barrier(0);
      __builtin_amdgcn_s_setprio(1);
#pragma unroll
      for (int j = 0; j < 4; ++j)
#pragma unroll
        for (int n = 0; n < 4; ++n)
          acc[4 + j][n] = __builtin_amdgcn_mfma_f32_16x16x32_bf16(a1[j], bA[n], acc[4 + j][n], 0, 0, 0);
      __builtin_amdgcn_s_setprio(0);
#pragma unroll
      for (int n = 0; n < 4; ++n)
        bB[n] = *(const bf16x8*)(Breg[d] + rowB0 + n * 2048 + cko[1]);
      __builtin_amdgcn_sched_barrier(0);
      __builtin_amdgcn_s_barrier();

      // ---- ph2: MFMA P0 x bB(kh1); issue a1 <- P1,kh1
#pragma unroll
      for (int j = 0; j < 4; ++j)
        a1[j] = *(const bf16x8*)(Areg[d] + rowA0 + (4 + j) * 2048 + cko[1]);
      asm volatile("s_waitcnt lgkmcnt(4)" ::: "memory");
      __builtin_amdgcn_sched_barrier(0);
      __builtin_amdgcn_s_setprio(1);
#pragma unroll
      for (int j = 0; j < 4; ++j)
#pragma unroll
        for (int n = 0; n < 4; ++n)
          acc[j][n] = __builtin_amdgcn_mfma_f32_16x16x32_bf16(a0[j], bB[n], acc[j][n], 0, 0, 0);
      __builtin_amdgcn_s_setprio(0);
      __builtin_amdgcn_s_barrier();

      // ---- ph3: MFMA P1 x bB; stage B(T+2); gate; cross-tile pre-reads
      if (pf) { stageHalf(u+2+d,1,0,Bc,ldBb); stageHalf(u+2+d,1,1,Bc,ldBb); }
      const bool haveNext = (d == 0) || pf;
      if (haveNext) {
        if (d == 0 && !pf) asm volatile("s_waitcnt vmcnt(0)" ::: "memory");
        else               asm volatile("s_waitcnt vmcnt(4)" ::: "memory");
        __builtin_amdgcn_s_barrier();
#pragma unroll
        for (int n = 0; n < 4; ++n)
          bA[n] = *(const bf16x8*)(Breg[d^1] + rowB0 + n * 2048 + cko[0]);
#pragma unroll
        for (int j = 0; j < 4; ++j)
          a0[j] = *(const bf16x8*)(Areg[d^1] + rowA0 + j * 2048 + cko[0]);
        asm volatile("s_waitcnt lgkmcnt(8)" ::: "memory");
      } else {
        asm volatile("s_waitcnt lgkmcnt(0)" ::: "memory");
      }
      __builtin_amdgcn_sched_barrier(0);
      __builtin_amdgcn_s_setprio(1);
#pragma unroll
      for (int j = 0; j < 4; ++j)
#pragma unroll
        for (int n = 0; n < 4; ++n)
          acc[4 + j][n] = __builtin_amdgcn_mfma_f32_16x16x32_bf16(a1[j], bB[n], acc[4 + j][n], 0, 0, 0);
      __builtin_amdgcn_s_setprio(0);
      __builtin_amdgcn_s_barrier();
    }
  }

  // epilogue: fragment layout col=lane&15, row=(lane>>4)*4+reg [m89/m91],
  // rows r=0..3 consecutive -> contiguous vector in transposed write.
  const long row0 = (long)bm * 256 + wm * 128 + (lane >> 4) * 4;
  const int col0 = bn * 256 + wn * 64 + (lane & 15);
#pragma unroll
  for (int m = 0; m < 8; ++m) {
#pragma unroll
    for (int n = 0; n < 4; ++n) {
      long row = row0 + m * 16;
      long col = col0 + n * 16;
      long base = col * (long)ldT + row;
      if constexpr (sizeof(OutT) == 2) {
        ushort4 st;
        st.x = f2bf(acc[m][n][0] * alpha); st.y = f2bf(acc[m][n][1] * alpha);
        st.z = f2bf(acc[m][n][2] * alpha); st.w = f2bf(acc[m][n][3] * alpha);
        *(ushort4*)((unsigned short*)C + base) = st;
      } else {
        float4 st;
        st.x = acc[m][n][0] * alpha; st.y = acc[m][n][1] * alpha;
        st.z = acc[m][n][2] * alpha; st.w = acc[m][n][3] * alpha;
        *(float4*)((float*)C + base) = st;
      }
    }
  }
}

// in-place row softmax on bf16 rows of length C (C == 2048, 256 thr * 8)
__global__ __launch_bounds__(256) void softmax_inplace(unsigned short* __restrict__ s, int C) {
  __shared__ float red[8];
  long row = blockIdx.x;
  unsigned short* p = s + row * (long)C;
  int tid = threadIdx.x, lane = tid & 63, w = tid >> 6;
  bf16x8 raw = *(const bf16x8*)(p + tid * 8);
  float v[8];
  float mx = -3.4e38f;
#pragma unroll
  for (int j = 0; j < 8; ++j) { v[j] = bf2f((unsigned short)raw[j]); mx = fmaxf(mx, v[j]); }
#pragma unroll
  for (int o = 32; o > 0; o >>= 1) mx = fmaxf(mx, __shfl_xor(mx, o));
  if (lane == 0) red[w] = mx;
  __syncthreads();
  mx = fmaxf(fmaxf(red[0], red[1]), fmaxf(red[2], red[3]));
  float sum = 0.f;
#pragma unroll
  for (int j = 0; j < 8; ++j) { v[j] = __expf(v[j] - mx); sum += v[j]; }
#pragma unroll
  for (int o = 32; o > 0; o >>= 1) sum += __shfl_xor(sum, o);
  if (lane == 0) red[4 + w] = sum;
  __syncthreads();
  float inv = 1.f / (red[4] + red[5] + red[6] + red[7]);
  bf16x8 o8;
#pragma unroll
  for (int j = 0; j < 8; ++j) o8[j] = (short)f2bf(v[j] * inv);
  *(bf16x8*)(p + tid * 8) = o8;
}

extern "C" void kernel_launch(void* const* d_in, const int* in_sizes, int n_in,
                              void* d_out, int out_size, void* d_ws, size_t ws_size,
                              hipStream_t stream) {
  (void)in_sizes; (void)n_in; (void)out_size; (void)ws_size;
  const float* x  = (const float*)d_in[0];
  const float* Wq = (const float*)d_in[1];
  const float* Wk = (const float*)d_in[2];
  const float* Wv = (const float*)d_in[3];
  const float* Wo = (const float*)d_in[4];
  const int B = 8, S = 2048, D = 1024;
  const long MB = 1 << 20;
  char* w = (char*)d_ws;
  unsigned short* Wqb = (unsigned short*)(w + 0 * MB);
  unsigned short* Wkb = (unsigned short*)(w + 2 * MB);
  unsigned short* Wvb = (unsigned short*)(w + 4 * MB);
  unsigned short* Wob = (unsigned short*)(w + 6 * MB);
  unsigned short* xb  = (unsigned short*)(w + 8 * MB);
  unsigned short* qb  = (unsigned short*)(w + 40 * MB);
  unsigned short* kb  = (unsigned short*)(w + 72 * MB);
  unsigned short* vt  = (unsigned short*)(w + 104 * MB); // V^T as [D][B*S] (32MB)
  unsigned short* wb  = xb;  // x dead after projections
  unsigned short* attn = (unsigned short*)d_out;
  float* out = (float*)d_out;

  long nx = (long)B * S * D;
  long nw = (long)D * D;

  const int LDSB = 131072;
  hipFuncSetAttribute((const void*)gemm_tt<unsigned short>,
                      hipFuncAttributeMaxDynamicSharedMemorySize, LDSB);
  hipFuncSetAttribute((const void*)gemm_tt<float>,
                      hipFuncAttributeMaxDynamicSharedMemorySize, LDSB);

  cast_f32_bf16_k<<<(int)(nx / 2048), 256, 0, stream>>>(x, xb, nx);
  dim3 gW((int)(nw / 2048), 1, 4);
  cast4_f32_bf16_k<<<gW, 256, 0, stream>>>(Wq, Wk, Wv, Wo, Wqb, nw);

  // Q-proj (swapped): C = Wq @ x^T -> transposed-write = q [16384][1024]
  dim3 gQ(64, 4, 1);
  gemm_tt<unsigned short><<<gQ, 512, LDSB, stream>>>(
      Wqb, xb, qb, D, 0, 0, 0, D, D, D, 1.f);
  // K-proj (swapped)
  gemm_tt<unsigned short><<<gQ, 512, LDSB, stream>>>(
      Wkb, xb, kb, D, 0, 0, 0, D, D, D, 1.f);
  // V-proj (unswapped): Cfrag[xrow][d] -> transposed-write ldT=B*S gives
  // vt[d*16384 + xrow] = [D][B*S]  (exactly what PV consumes)
  dim3 gV(4, 64, 1);
  gemm_tt<unsigned short><<<gV, 512, LDSB, stream>>>(
      xb, Wvb, vt, D, 0, 0, 0, D, D, B * S, 1.f);

  // scores (swapped): C = k @ q^T = scores^T -> transposed-write = scores row-major
  dim3 gS(8, 8, B);
  gemm_tt<unsigned short><<<gS, 512, LDSB, stream>>>(
      kb, qb, attn, D, (long)S * D, (long)S * D, (long)S * S, D, D, S, 0.03125f);

  softmax_inplace<<<B * S, 256, 0, stream>>>(attn, S);

  // PV (swapped): A = vt [D][B*S] (batch col-offset S), B = attn;
  // Cfrag[d][s] -> transposed-write = wb [16384][1024] row-major
  dim3 gPV(8, 4, B);
  gemm_tt<unsigned short><<<gPV, 512, LDSB, stream>>>(
      vt, attn, wb, S, (long)S, (long)S * S, (long)S * D, B * S, S, D, 1.f);

  // out-proj (swapped, fp32): C = Wo @ wb^T -> transposed float4-write = out
  dim3 gO(64, 4, 1);
  gemm_tt<float><<<gO, 512, LDSB, stream>>>(
      Wob, wb, out, D, 0, 0, 0, D, D, D, 1.f);
}

// Round 13
// 392.307 us; speedup vs baseline: 1.9571x; 1.9571x over previous
//
#include <hip/hip_runtime.h>
#include <hip/hip_bf16.h>
#include <stdint.h>

typedef short bf16x8 __attribute__((ext_vector_type(8)));
typedef float f32x4 __attribute__((ext_vector_type(4)));

__device__ __forceinline__ unsigned short f2bf(float x) {
  uint32_t u = __builtin_bit_cast(uint32_t, x);
  u += 0x7FFFu + ((u >> 16) & 1u);
  return (unsigned short)(u >> 16);
}
__device__ __forceinline__ float bf2f(unsigned short u) {
  uint32_t v = ((uint32_t)u) << 16;
  return __builtin_bit_cast(float, v);
}

__device__ __forceinline__ void gl2lds16(const void* g, void* l) {
  __builtin_amdgcn_global_load_lds(
      (const __attribute__((address_space(1))) unsigned int*)g,
      (__attribute__((address_space(3))) unsigned int*)l, 16, 0, 0);
}

__global__ __launch_bounds__(256) void cast_f32_bf16_k(
    const float* __restrict__ s, unsigned short* __restrict__ d, long n) {
  long i = ((long)blockIdx.x * 256 + threadIdx.x) * 8;
  if (i >= n) return;
  float4 a = *(const float4*)(s + i);
  float4 b = *(const float4*)(s + i + 4);
  bf16x8 o;
  o[0] = (short)f2bf(a.x); o[1] = (short)f2bf(a.y);
  o[2] = (short)f2bf(a.z); o[3] = (short)f2bf(a.w);
  o[4] = (short)f2bf(b.x); o[5] = (short)f2bf(b.y);
  o[6] = (short)f2bf(b.z); o[7] = (short)f2bf(b.w);
  *(bf16x8*)(d + i) = o;
}

__global__ __launch_bounds__(256) void cast4_f32_bf16_k(
    const float* __restrict__ s0, const float* __restrict__ s1,
    const float* __restrict__ s2, const float* __restrict__ s3,
    unsigned short* __restrict__ d, long n) {
  const float* s = blockIdx.z == 0 ? s0 : blockIdx.z == 1 ? s1 : blockIdx.z == 2 ? s2 : s3;
  long i = ((long)blockIdx.x * 256 + threadIdx.x) * 8;
  if (i >= n) return;
  float4 a = *(const float4*)(s + i);
  float4 b = *(const float4*)(s + i + 4);
  bf16x8 o;
  o[0] = (short)f2bf(a.x); o[1] = (short)f2bf(a.y);
  o[2] = (short)f2bf(a.z); o[3] = (short)f2bf(a.w);
  o[4] = (short)f2bf(b.x); o[5] = (short)f2bf(b.y);
  o[6] = (short)f2bf(b.z); o[7] = (short)f2bf(b.w);
  *(bf16x8*)(d + blockIdx.z * n + i) = o;
}

// ============================================================================
// 256x128 pipelined GEMM, TRANSPOSED OUTPUT:
//   Cfrag[m][n] = sum_k A[m][k]*B[n][k]; dst[col*ldT + row] (coalesced vec4).
// R13 vs R12: 16 MFMA/phase via SMALLER BN (128), not more registers.
// 8 waves = 4M x 2N, wave tile 64x64, acc[4][4] = 64 AGPR. Data regs =
// 64 acc + b2[2][4][2] 64 + a01/a23 32 = 160 (== R10's proven-fit budget).
// LDS 96KB: per buf {A0 16K (rows 0-127), A1 16K (128-255), B 16K}. Swizzle
// phys_col = col ^ ((row&7)<<4) (R3-verified: 0 conflicts).
// 2 phases/K-tile, 3 barriers/tile:
//  ph0: stage A(t+1)x4; issue a23[4]; lgkm(4) [drains prev cross-reads=12];
//       16 MFMA m01 x b2[d]; barrier.
//  ph1: stage B(t+2)x2; gate vmcnt(2) [steady: drains B(t+1)+A(t+1), leaves
//       B(t+2); t=nt-2: vmcnt(0)]; barrier; cross-read b2[d^1][8]+a01[4]
//       from buf d^1; lgkm(12) [drains a23]; 16 MFMA m23 x b2[d]; barrier.
// vm induction (hand-verified): in-flight before ph0-stage = B(t+1)[2];
// +A(t+1)4 +B(t+2)2 = 8; gate(2) drains exactly B(t+1)+A(t+1). WAR audit:
// A(t+1)->buf d^1 staged at ph0(t): d^1-readers drained at ph0(t-1) wait +
// barrier. B(t+2)->buf d staged at ph1(t): b2[d] cross-reads drained at
// ph0(t) wait + barrier. 2-tile unroll keeps b2[d] indices compile-time.
// ============================================================================
template <typename OutT>
__global__ __launch_bounds__(512, 2) void gemm_tt(
    const unsigned short* __restrict__ A, const unsigned short* __restrict__ B,
    OutT* __restrict__ C, int K,
    long sA, long sB, long sC, int ldA, int ldB, int ldT, float alpha) {
  extern __shared__ __align__(16) char smem[];
  const int bz = blockIdx.z;
  const int gx = gridDim.x;
  const int nwg = gx * gridDim.y;  // must be %8==0
  const int idx = blockIdx.y * gx + blockIdx.x;
  const int wg = (idx & 7) * (nwg >> 3) + (idx >> 3);
  const int bm = wg / gx, bn = wg % gx;

  const int tid = threadIdx.x, lane = tid & 63, wave = tid >> 6;
  const int wm = wave >> 1, wn = wave & 1;

  const long ldAb = (long)ldA * 2, ldBb = (long)ldB * 2;
  const char* Ac = (const char*)(A + (long)bz * sA) + (long)bm * 256 * ldAb;
  const char* Bc = (const char*)(B + (long)bz * sB) + (long)bn * 128 * ldBb;
  C += (long)bz * sC;

  const int sr8 = tid >> 3;
  const int scolx = (((tid & 7) ^ ((tid >> 3) & 7)) << 4);  // pre-swizzled col

  // stage tile t's A (4 gl2lds: 256x64) or B (2 gl2lds: 128x64) into buf t&1
  auto stageA = [&](int t) {
    char* base = smem + (t & 1) * 49152;
    const long ktb = (long)t << 7;
#pragma unroll
    for (int h = 0; h < 2; ++h)
#pragma unroll
      for (int c = 0; c < 2; ++c)
        gl2lds16(Ac + (long)(h * 128 + c * 64 + sr8) * ldAb + ktb + scolx,
                 base + h * 16384 + c * 8192 + tid * 16);
  };
  auto stageB = [&](int t) {
    char* base = smem + (t & 1) * 49152 + 32768;
    const long ktb = (long)t << 7;
#pragma unroll
    for (int c = 0; c < 2; ++c)
      gl2lds16(Bc + (long)(c * 64 + sr8) * ldBb + ktb + scolx,
               base + c * 8192 + tid * 16);
  };

  const int cko[2] = { (((lane >> 4) << 4) ^ ((lane & 7) << 4)),
                       ((64 | ((lane >> 4) << 4)) ^ ((lane & 7) << 4)) };
  // wave's A region: half = wm>>1, row base (wm&1)*64; B region at +32768
  const int Aoff = (wm >> 1) * 16384 + ((wm & 1) * 64 + (lane & 15)) * 128;
  const int Boff = 32768 + (wn * 64 + (lane & 15)) * 128;

  f32x4 acc[4][4] = {};
  bf16x8 b2[2][4][2], a01[2][2], a23[2][2];

  // prologue: B(0)x2, A(0)x4, B(1)x2 -> vmcnt(2) leaves B(1); pre-read 12
  stageB(0); stageA(0); stageB(1);
  asm volatile("s_waitcnt vmcnt(2)" ::: "memory");
  __builtin_amdgcn_s_barrier();
#pragma unroll
  for (int nf = 0; nf < 4; ++nf)
#pragma unroll
    for (int kh = 0; kh < 2; ++kh)
      b2[0][nf][kh] = *(const bf16x8*)(smem + Boff + nf * 2048 + cko[kh]);
#pragma unroll
  for (int j = 0; j < 2; ++j)
#pragma unroll
    for (int kh = 0; kh < 2; ++kh)
      a01[j][kh] = *(const bf16x8*)(smem + Aoff + j * 2048 + cko[kh]);

  const int nt = K >> 6;         // even, >= 4
  const int niter = nt >> 1;
  for (int i = 0; i < niter; ++i) {
    const int u = 2 * i;
    const bool pf = (i + 1 < niter);
#pragma unroll
    for (int d = 0; d < 2; ++d) {
      const int t = u + d;
      const char* bufc = smem + d * 49152;
      const char* bufn = smem + (d ^ 1) * 49152;

      // ---- ph0: 16 MFMA m01 x b2[d]
      if (d == 0 || pf) stageA(t + 1);
#pragma unroll
      for (int j = 0; j < 2; ++j)
#pragma unroll
        for (int kh = 0; kh < 2; ++kh)
          a23[j][kh] = *(const bf16x8*)(bufc + Aoff + (2 + j) * 2048 + cko[kh]);
      asm volatile("s_waitcnt lgkmcnt(4)" ::: "memory");
      __builtin_amdgcn_sched_barrier(0);
      __builtin_amdgcn_s_setprio(1);
#pragma unroll
      for (int kh = 0; kh < 2; ++kh)
#pragma unroll
        for (int j = 0; j < 2; ++j)
#pragma unroll
          for (int nf = 0; nf < 4; ++nf)
            acc[j][nf] = __builtin_amdgcn_mfma_f32_16x16x32_bf16(
                a01[j][kh], b2[d][nf][kh], acc[j][nf], 0, 0, 0);
      __builtin_amdgcn_s_setprio(0);
      __builtin_amdgcn_s_barrier();

      // ---- ph1: 16 MFMA m23 x b2[d]; gate + cross-reads for tile t+1
      if (pf) stageB(t + 2);
      const bool haveNext = (d == 0) || pf;
      if (haveNext) {
        if (d == 0 && !pf) asm volatile("s_waitcnt vmcnt(0)" ::: "memory");
        else               asm volatile("s_waitcnt vmcnt(2)" ::: "memory");
        __builtin_amdgcn_s_barrier();
#pragma unroll
        for (int nf = 0; nf < 4; ++nf)
#pragma unroll
          for (int kh = 0; kh < 2; ++kh)
            b2[d ^ 1][nf][kh] = *(const bf16x8*)(bufn + Boff + nf * 2048 + cko[kh]);
#pragma unroll
        for (int j = 0; j < 2; ++j)
#pragma unroll
          for (int kh = 0; kh < 2; ++kh)
            a01[j][kh] = *(const bf16x8*)(bufn + Aoff + j * 2048 + cko[kh]);
        asm volatile("s_waitcnt lgkmcnt(12)" ::: "memory");
      } else {
        asm volatile("s_waitcnt lgkmcnt(0)" ::: "memory");
      }
      __builtin_amdgcn_sched_barrier(0);
      __builtin_amdgcn_s_setprio(1);
#pragma unroll
      for (int kh = 0; kh < 2; ++kh)
#pragma unroll
        for (int j = 0; j < 2; ++j)
#pragma unroll
          for (int nf = 0; nf < 4; ++nf)
            acc[2 + j][nf] = __builtin_amdgcn_mfma_f32_16x16x32_bf16(
                a23[j][kh], b2[d][nf][kh], acc[2 + j][nf], 0, 0, 0);
      __builtin_amdgcn_s_setprio(0);
      __builtin_amdgcn_s_barrier();
    }
  }

  // epilogue: fragment layout col=lane&15, row=(lane>>4)*4+reg [m89/m91],
  // rows r=0..3 consecutive -> contiguous vector in transposed write.
  const long row0 = (long)bm * 256 + wm * 64 + (lane >> 4) * 4;
  const int col0 = bn * 128 + wn * 64 + (lane & 15);
#pragma unroll
  for (int mf = 0; mf < 4; ++mf) {
#pragma unroll
    for (int nf = 0; nf < 4; ++nf) {
      long row = row0 + mf * 16;
      long col = col0 + nf * 16;
      long base = col * (long)ldT + row;
      if constexpr (sizeof(OutT) == 2) {
        ushort4 st;
        st.x = f2bf(acc[mf][nf][0] * alpha); st.y = f2bf(acc[mf][nf][1] * alpha);
        st.z = f2bf(acc[mf][nf][2] * alpha); st.w = f2bf(acc[mf][nf][3] * alpha);
        *(ushort4*)((unsigned short*)C + base) = st;
      } else {
        float4 st;
        st.x = acc[mf][nf][0] * alpha; st.y = acc[mf][nf][1] * alpha;
        st.z = acc[mf][nf][2] * alpha; st.w = acc[mf][nf][3] * alpha;
        *(float4*)((float*)C + base) = st;
      }
    }
  }
}

// in-place row softmax on bf16 rows of length C (C == 2048, 256 thr * 8)
__global__ __launch_bounds__(256) void softmax_inplace(unsigned short* __restrict__ s, int C) {
  __shared__ float red[8];
  long row = blockIdx.x;
  unsigned short* p = s + row * (long)C;
  int tid = threadIdx.x, lane = tid & 63, w = tid >> 6;
  bf16x8 raw = *(const bf16x8*)(p + tid * 8);
  float v[8];
  float mx = -3.4e38f;
#pragma unroll
  for (int j = 0; j < 8; ++j) { v[j] = bf2f((unsigned short)raw[j]); mx = fmaxf(mx, v[j]); }
#pragma unroll
  for (int o = 32; o > 0; o >>= 1) mx = fmaxf(mx, __shfl_xor(mx, o));
  if (lane == 0) red[w] = mx;
  __syncthreads();
  mx = fmaxf(fmaxf(red[0], red[1]), fmaxf(red[2], red[3]));
  float sum = 0.f;
#pragma unroll
  for (int j = 0; j < 8; ++j) { v[j] = __expf(v[j] - mx); sum += v[j]; }
#pragma unroll
  for (int o = 32; o > 0; o >>= 1) sum += __shfl_xor(sum, o);
  if (lane == 0) red[4 + w] = sum;
  __syncthreads();
  float inv = 1.f / (red[4] + red[5] + red[6] + red[7]);
  bf16x8 o8;
#pragma unroll
  for (int j = 0; j < 8; ++j) o8[j] = (short)f2bf(v[j] * inv);
  *(bf16x8*)(p + tid * 8) = o8;
}

extern "C" void kernel_launch(void* const* d_in, const int* in_sizes, int n_in,
                              void* d_out, int out_size, void* d_ws, size_t ws_size,
                              hipStream_t stream) {
  (void)in_sizes; (void)n_in; (void)out_size; (void)ws_size;
  const float* x  = (const float*)d_in[0];
  const float* Wq = (const float*)d_in[1];
  const float* Wk = (const float*)d_in[2];
  const float* Wv = (const float*)d_in[3];
  const float* Wo = (const float*)d_in[4];
  const int B = 8, S = 2048, D = 1024;
  const long MB = 1 << 20;
  char* w = (char*)d_ws;
  unsigned short* Wqb = (unsigned short*)(w + 0 * MB);
  unsigned short* Wkb = (unsigned short*)(w + 2 * MB);
  unsigned short* Wvb = (unsigned short*)(w + 4 * MB);
  unsigned short* Wob = (unsigned short*)(w + 6 * MB);
  unsigned short* xb  = (unsigned short*)(w + 8 * MB);
  unsigned short* qb  = (unsigned short*)(w + 40 * MB);
  unsigned short* kb  = (unsigned short*)(w + 72 * MB);
  unsigned short* vt  = (unsigned short*)(w + 104 * MB); // V^T as [D][B*S] (32MB)
  unsigned short* wb  = xb;  // x dead after projections
  unsigned short* attn = (unsigned short*)d_out;
  float* out = (float*)d_out;

  long nx = (long)B * S * D;
  long nw = (long)D * D;

  const int LDSB = 98304;
  hipFuncSetAttribute((const void*)gemm_tt<unsigned short>,
                      hipFuncAttributeMaxDynamicSharedMemorySize, LDSB);
  hipFuncSetAttribute((const void*)gemm_tt<float>,
                      hipFuncAttributeMaxDynamicSharedMemorySize, LDSB);

  cast_f32_bf16_k<<<(int)(nx / 2048), 256, 0, stream>>>(x, xb, nx);
  dim3 gW((int)(nw / 2048), 1, 4);
  cast4_f32_bf16_k<<<gW, 256, 0, stream>>>(Wq, Wk, Wv, Wo, Wqb, nw);

  // Q-proj (swapped): A=Wq (M=1024, gy=4), B=xb (N=16384, gx=128) -> q row-major
  dim3 gQ(128, 4, 1);
  gemm_tt<unsigned short><<<gQ, 512, LDSB, stream>>>(
      Wqb, xb, qb, D, 0, 0, 0, D, D, D, 1.f);
  gemm_tt<unsigned short><<<gQ, 512, LDSB, stream>>>(
      Wkb, xb, kb, D, 0, 0, 0, D, D, D, 1.f);
  // V-proj (unswapped): A=xb (M=16384, gy=64), B=Wv (N=1024, gx=8) -> vt [D][B*S]
  dim3 gV(8, 64, 1);
  gemm_tt<unsigned short><<<gV, 512, LDSB, stream>>>(
      xb, Wvb, vt, D, 0, 0, 0, D, D, B * S, 1.f);

  // scores (swapped): A=k (M=2048, gy=8), B=q (N=2048, gx=16) -> attn row-major
  dim3 gS(16, 8, B);
  gemm_tt<unsigned short><<<gS, 512, LDSB, stream>>>(
      kb, qb, attn, D, (long)S * D, (long)S * D, (long)S * S, D, D, S, 0.03125f);

  softmax_inplace<<<B * S, 256, 0, stream>>>(attn, S);

  // PV (swapped): A=vt (M=1024, gy=4, batch col-offset S), B=attn (N=2048, gx=16)
  dim3 gPV(16, 4, B);
  gemm_tt<unsigned short><<<gPV, 512, LDSB, stream>>>(
      vt, attn, wb, S, (long)S, (long)S * S, (long)S * D, B * S, S, D, 1.f);

  // out-proj (swapped, fp32): A=Wo (gy=4), B=wb (gx=128) -> out row-major
  dim3 gO(128, 4, 1);
  gemm_tt<float><<<gO, 512, LDSB, stream>>>(
      Wob, wb, out, D, 0, 0, 0, D, D, D, 1.f);
}